// Round 1
// baseline (620.224 us; speedup 1.0000x reference)
//
#include <hip/hip_runtime.h>
#include <hip/hip_bf16.h>
#include <stdint.h>

// Problem: B=32, LH=2048, LT=2048, D=768
//   z1 = H @ W            [B, LH, D]
//   alpha = tanh(max_l (z1 @ T^T))   [B, LT]   (tanh monotone => max then tanh)
//   HT = alpha @ T        [B, D]
#define NB 32
#define LHD 2048
#define LTD 2048
#define DD 768

using bf16x8 = __attribute__((ext_vector_type(8))) __bf16;
using f32x4  = __attribute__((ext_vector_type(4))) float;
typedef unsigned short u16;

__device__ __forceinline__ u16 f2bf(float f) {
    union { float f; uint32_t u; } v; v.f = f;
    uint32_t u = v.u + 0x7FFFu + ((v.u >> 16) & 1u);
    return (u16)(u >> 16);
}

__device__ __forceinline__ void glds16(const u16* g, u16* l) {
    __builtin_amdgcn_global_load_lds(
        (const __attribute__((address_space(1))) unsigned int*)g,
        (__attribute__((address_space(3))) unsigned int*)l,
        16, 0, 0);
}

// ---------------- conversion kernels ----------------
__global__ void k_convert(const float* __restrict__ in, u16* __restrict__ out, int n4) {
    int i = blockIdx.x * 256 + threadIdx.x;
    int stride = gridDim.x * 256;
    for (; i < n4; i += stride) {
        float4 v = reinterpret_cast<const float4*>(in)[i];
        ushort4 o;
        o.x = f2bf(v.x); o.y = f2bf(v.y); o.z = f2bf(v.z); o.w = f2bf(v.w);
        reinterpret_cast<ushort4*>(out)[i] = o;
    }
}

// WT[n][k] = W[k][n], 768x768, bf16
__global__ void k_transpose_w(const float* __restrict__ W, u16* __restrict__ WT) {
    int idx = blockIdx.x * 256 + threadIdx.x;   // coalesced read of W
    int k = idx / DD, n = idx % DD;
    WT[(size_t)n * DD + k] = f2bf(W[idx]);
}

// ---------------- main GEMM (A [M,K] row-major bf16, Bt [N,K] row-major bf16) ----------------
// COLMAX: instead of storing C, write per-(block-row) column maxes to Pb[b][mt][N]
template<bool COLMAX, int M, int N, bool SHARED_B>
__global__ __launch_bounds__(256)
void k_gemm_bt(const u16* __restrict__ Ab, const u16* __restrict__ Bb,
               u16* __restrict__ Cb, float* __restrict__ Pb)
{
    constexpr int K = DD;
    constexpr int BM = 128, BN = 128, BK = 64;
    constexpr int MT = M / BM, NT = N / BN, TPB = MT * NT;

    const int bx = blockIdx.x;
    const int batch = bx / TPB;
    const int t = bx % TPB;
    const int mt = t / NT, nt = t % NT;

    const u16* A  = Ab + (size_t)batch * M * K + (size_t)mt * BM * K;
    const u16* Bt = Bb + (SHARED_B ? (size_t)0 : (size_t)batch * N * K) + (size_t)nt * BN * K;

    __shared__ __align__(16) u16 As[BM][BK];
    __shared__ __align__(16) u16 Bs[BN][BK];

    const int tid  = threadIdx.x;
    const int wave = tid >> 6;
    const int lane = tid & 63;

    // staging: per matrix 128x64 bf16 = 1024 16B-chunks; wave w issue i covers
    // chunks [w*256 + i*64 + lane]; linear LDS => row = chunk>>3, col16 = chunk&7
    const int srow = wave * 32 + (lane >> 3);
    const int scol = (lane & 7) * 8;

    const int wr = wave >> 1, wc = wave & 1;  // 2x2 wave grid, each 64x64
    const int fr = lane & 15;
    const int kq = lane >> 4;

    f32x4 acc[4][4] = {};

    for (int k0 = 0; k0 < K; k0 += BK) {
        #pragma unroll
        for (int i = 0; i < 4; ++i) {
            const int r = srow + i * 8;
            glds16(A  + (size_t)r * K + k0 + scol, &As[0][0] + wave * 2048 + i * 512);
            glds16(Bt + (size_t)r * K + k0 + scol, &Bs[0][0] + wave * 2048 + i * 512);
        }
        __syncthreads();
        #pragma unroll
        for (int kk = 0; kk < 2; ++kk) {
            bf16x8 af[4], bfr[4];
            #pragma unroll
            for (int m = 0; m < 4; ++m)
                af[m] = *reinterpret_cast<const bf16x8*>(&As[wr*64 + m*16 + fr][kk*32 + kq*8]);
            #pragma unroll
            for (int n = 0; n < 4; ++n)
                bfr[n] = *reinterpret_cast<const bf16x8*>(&Bs[wc*64 + n*16 + fr][kk*32 + kq*8]);
            #pragma unroll
            for (int m = 0; m < 4; ++m)
                #pragma unroll
                for (int n = 0; n < 4; ++n)
                    acc[m][n] = __builtin_amdgcn_mfma_f32_16x16x32_bf16(af[m], bfr[n], acc[m][n], 0, 0, 0);
        }
        __syncthreads();
    }

    if constexpr (!COLMAX) {
        // C/D frag layout: col = lane&15, row = (lane>>4)*4 + reg  [verified m89/m91]
        u16* C = Cb + (size_t)batch * M * N + (size_t)(mt*BM + wr*64) * N + nt*BN + wc*64;
        #pragma unroll
        for (int m = 0; m < 4; ++m)
            #pragma unroll
            for (int n = 0; n < 4; ++n)
                #pragma unroll
                for (int r = 0; r < 4; ++r)
                    C[(size_t)(m*16 + kq*4 + r) * N + n*16 + fr] = f2bf(acc[m][n][r]);
    } else {
        __shared__ float cmax[2][BN];
        #pragma unroll
        for (int n = 0; n < 4; ++n) {
            float v = -3.4e38f;
            #pragma unroll
            for (int m = 0; m < 4; ++m)
                #pragma unroll
                for (int r = 0; r < 4; ++r)
                    v = fmaxf(v, acc[m][n][r]);
            // combine the 4 kq row-groups (rows within this wave's 64)
            v = fmaxf(v, __shfl_xor(v, 16));
            v = fmaxf(v, __shfl_xor(v, 32));
            if (lane < 16)
                cmax[wr][wc*64 + n*16 + fr] = v;
        }
        __syncthreads();
        if (tid < BN) {
            float v = fmaxf(cmax[0][tid], cmax[1][tid]);
            Pb[((size_t)batch * MT + mt) * N + nt * BN + tid] = v;
        }
    }
}

// alpha[b][t] = tanh(max over 16 row-tiles of partial)
__global__ void k_alpha(const float* __restrict__ Pb, float* __restrict__ alpha) {
    int idx = blockIdx.x * 256 + threadIdx.x;   // NB*LTD
    int b = idx / LTD, tt = idx % LTD;
    float m = -3.4e38f;
    #pragma unroll
    for (int lt = 0; lt < 16; ++lt)
        m = fmaxf(m, Pb[((size_t)b * 16 + lt) * LTD + tt]);
    alpha[idx] = tanhf(m);
}

// p2[b][tc][d] = sum over 256 t of alpha*T (f32 inputs for accuracy)
__global__ void k_ht_partial(const float* __restrict__ T, const float* __restrict__ alpha,
                             float* __restrict__ p2) {
    int bx = blockIdx.x;            // NB*3*8
    int tc = bx & 7;
    int r  = bx >> 3;
    int dc = r % 3, b = r / 3;
    int d = dc * 256 + threadIdx.x;
    const float* Tp = T + (size_t)b * LTD * DD + (size_t)tc * 256 * DD + d;
    const float* al = alpha + b * LTD + tc * 256;
    float s = 0.f;
    for (int t2 = 0; t2 < 256; ++t2)
        s += al[t2] * Tp[(size_t)t2 * DD];
    p2[((size_t)b * 8 + tc) * DD + d] = s;
}

__global__ void k_ht_reduce(const float* __restrict__ p2, float* __restrict__ out) {
    int idx = blockIdx.x * 256 + threadIdx.x;   // NB*DD = 24576
    int b = idx / DD, d = idx % DD;
    float s = 0.f;
    #pragma unroll
    for (int tc = 0; tc < 8; ++tc)
        s += p2[((size_t)b * 8 + tc) * DD + d];
    out[idx] = s;
}

extern "C" void kernel_launch(void* const* d_in, const int* in_sizes, int n_in,
                              void* d_out, int out_size, void* d_ws, size_t ws_size,
                              hipStream_t stream) {
    const float* H = (const float*)d_in[0];
    const float* T = (const float*)d_in[1];
    const float* W = (const float*)d_in[2];
    float* out = (float*)d_out;

    char* ws = (char*)d_ws;
    size_t off = 0;
    auto carve = [&](size_t bytes) -> void* {
        void* p = ws + off;
        off += (bytes + 255) & ~(size_t)255;
        return p;
    };
    u16*   R1    = (u16*)carve((size_t)NB * LHD * DD * 2);   // Hb, later reused as Tb
    u16*   z1    = (u16*)carve((size_t)NB * LHD * DD * 2);
    u16*   WT    = (u16*)carve((size_t)DD * DD * 2);
    float* Pb    = (float*)carve((size_t)NB * 16 * LTD * 4);
    float* alpha = (float*)carve((size_t)NB * LTD * 4);
    float* p2    = (float*)carve((size_t)NB * 8 * DD * 4);

    // ws too small -> bail (shows as clean absmax failure == max|ref|, not a crash)
    if (ws_size < off) return;

    const int n4 = NB * LHD * DD / 4;

    // 1. Hb = bf16(H)
    k_convert<<<4096, 256, 0, stream>>>(H, R1, n4);
    // 2. WT = bf16(W^T)
    k_transpose_w<<<(DD * DD) / 256, 256, 0, stream>>>(W, WT);
    // 3. z1 = Hb @ W      (A=[LH,D], Bt=WT [D rows, D], shared across batch)
    k_gemm_bt<false, LHD, DD, true>
        <<<NB * (LHD/128) * (DD/128), 256, 0, stream>>>(R1, WT, z1, nullptr);
    // 4. Tb = bf16(T) into R1 (Hb dead now; stream-ordered)
    k_convert<<<4096, 256, 0, stream>>>(T, R1, n4);
    // 5. Pb[b][mt][t] = colmax over 128 rows of z1 @ T^T
    k_gemm_bt<true, LHD, LTD, false>
        <<<NB * (LHD/128) * (LTD/128), 256, 0, stream>>>(z1, R1, nullptr, Pb);
    // 6. alpha = tanh(max over mt)
    k_alpha<<<NB * LTD / 256, 256, 0, stream>>>(Pb, alpha);
    // 7-8. HT = alpha @ T  (f32)
    k_ht_partial<<<NB * 3 * 8, 256, 0, stream>>>(T, alpha, p2);
    k_ht_reduce<<<NB * DD / 256, 256, 0, stream>>>(p2, out);
}

// Round 2
// 491.288 us; speedup vs baseline: 1.2624x; 1.2624x over previous
//
#include <hip/hip_runtime.h>
#include <hip/hip_bf16.h>
#include <stdint.h>

// Problem: B=32, LH=2048, LT=2048, D=768
//   z1 = H @ W ; alpha = tanh(colmax(z1 @ T^T)) ; HT = alpha @ T
#define NB 32
#define LHD 2048
#define LTD 2048
#define DD 768

using bf16x8 = __attribute__((ext_vector_type(8))) __bf16;
using f32x4  = __attribute__((ext_vector_type(4))) float;
typedef unsigned short u16;

__device__ __forceinline__ u16 f2bf(float f) {
    union { float f; uint32_t u; } v; v.f = f;
    uint32_t u = v.u + 0x7FFFu + ((v.u >> 16) & 1u);
    return (u16)(u >> 16);
}

__device__ __forceinline__ void glds16(const u16* g, u16* l) {
    __builtin_amdgcn_global_load_lds(
        (const __attribute__((address_space(1))) unsigned int*)g,
        (__attribute__((address_space(3))) unsigned int*)l,
        16, 0, 0);
}

// ---------------- conversion kernels ----------------
__global__ void k_convert(const float* __restrict__ in, u16* __restrict__ out, int n4) {
    int i = blockIdx.x * 256 + threadIdx.x;
    int stride = gridDim.x * 256;
    for (; i < n4; i += stride) {
        float4 v = reinterpret_cast<const float4*>(in)[i];
        ushort4 o;
        o.x = f2bf(v.x); o.y = f2bf(v.y); o.z = f2bf(v.z); o.w = f2bf(v.w);
        reinterpret_cast<ushort4*>(out)[i] = o;
    }
}

__global__ void k_transpose_w(const float* __restrict__ W, u16* __restrict__ WT) {
    int idx = blockIdx.x * 256 + threadIdx.x;
    int k = idx / DD, n = idx % DD;
    WT[(size_t)n * DD + k] = f2bf(W[idx]);
}

// ---------------- 256x256-tile deep-pipelined GEMM ----------------
// A [M,K] row-major bf16; Bt [N,K] row-major bf16; K=768.
// 8 waves (2Mx4N), per-wave 128x64 output; BK=32; 4-buffer LDS ring;
// stage t+3 during tile t; vmcnt(8) counted waits; XOR-swizzled LDS.
template<bool COLMAX, int M, int N, bool SHARED_B>
__global__ __launch_bounds__(512, 2)
void k_gemm256(const u16* __restrict__ Ab, const u16* __restrict__ Bb,
               u16* __restrict__ Cb, float* __restrict__ Pb)
{
    constexpr int K  = DD;       // 768
    constexpr int BK = 32;
    constexpr int NT = K / BK;   // 24
    constexpr int MT = M / 256, NTC = N / 256, TPB = MT * NTC;
    static_assert(K % BK == 0, "K");

    // bijective XCD-aware swizzle (grids are multiples of 8)
    const int nwg = gridDim.x;
    const int w   = ((blockIdx.x & 7) * (nwg >> 3)) + (blockIdx.x >> 3);
    const int batch = w / TPB;
    const int rem   = w % TPB;
    const int mt = rem / NTC, nc = rem % NTC;

    const u16* A  = Ab + (size_t)batch * M * K + (size_t)mt * 256 * K;
    const u16* Bt = Bb + (SHARED_B ? (size_t)0 : (size_t)batch * N * K) + (size_t)nc * 256 * K;

    // A ring: [4][256][32] bf16 @ elem 0 (64KB); B ring @ elem 32768 (64KB)
    __shared__ __align__(16) u16 smem[65536];

    const int tid  = threadIdx.x;
    const int wave = tid >> 6;
    const int lane = tid & 63;
    const int wr = wave >> 2, wc = wave & 3;   // 2x4 wave grid
    const int fr = lane & 15, kq = lane >> 4;

    // --- staging address precompute (pre-swizzled GLOBAL source, linear LDS dest) ---
    // chunk c = wave*128 + j*64 + lane ; phys row rp=c>>2, phys 16B slot cp=c&3
    // logical k-chunk stored at cp is kq' = cp ^ ((rp>>1)&3)
    const int c0  = wave * 128 + lane;
    const int c1  = c0 + 64;
    const int rp0 = c0 >> 2, rp1 = c1 >> 2;
    const int g0  = rp0 * K + ((((c0 & 3) ^ ((rp0 >> 1) & 3))) << 3);  // elems
    const int g1  = rp1 * K + ((((c1 & 3) ^ ((rp1 >> 1) & 3))) << 3);
    const int sA  = wave * 1024;  // this wave's chunk block (elems), +512 for j=1

    // --- fragment read byte offsets (within one buffer), same XOR on read ---
    const int xr  = (fr >> 1) & 3;
    const int afb = (wr * 128 + fr) * 64 + ((kq ^ xr) << 4);
    const int bfb = (wc * 64  + fr) * 64 + ((kq ^ xr) << 4);

    auto stage = [&](int buf, int t) {
        const u16* Ag = A  + t * BK;
        const u16* Bg = Bt + t * BK;
        u16* s = smem + buf * 8192;
        glds16(Ag + g0, s + sA);
        glds16(Ag + g1, s + sA + 512);
        glds16(Bg + g0, s + 32768 + sA);
        glds16(Bg + g1, s + 32768 + sA + 512);
    };

    f32x4 acc[8][4] = {};

    // prologue: tiles 0,1,2 in flight; wait until tile 0 landed (12 issued, <=8 out)
    stage(0, 0); stage(1, 1); stage(2, 2);
    asm volatile("s_waitcnt vmcnt(8)" ::: "memory");
    __builtin_amdgcn_s_barrier();
    __builtin_amdgcn_sched_barrier(0);

    #pragma unroll 4
    for (int t = 0; t < NT; ++t) {
        const int buf = t & 3;
        if (t + 3 < NT) stage((t + 3) & 3, t + 3);   // WAR-safe: that buf's reads done at t-1's barrier

        const char* ca = (const char*)smem + buf * 16384;
        bf16x8 af[8], bv[4];
        #pragma unroll
        for (int m = 0; m < 8; ++m)
            af[m] = *(const bf16x8*)(ca + afb + m * 1024);
        #pragma unroll
        for (int n = 0; n < 4; ++n)
            bv[n] = *(const bf16x8*)(ca + 65536 + bfb + n * 1024);

        __builtin_amdgcn_s_setprio(1);
        #pragma unroll
        for (int m = 0; m < 8; ++m)
            #pragma unroll
            for (int n = 0; n < 4; ++n)
                acc[m][n] = __builtin_amdgcn_mfma_f32_16x16x32_bf16(af[m], bv[n], acc[m][n], 0, 0, 0);
        __builtin_amdgcn_s_setprio(0);

        // counted drain: leave tiles t+2,t+3 in flight; guarantees t+1 landed
        if (t < NT - 3)       asm volatile("s_waitcnt vmcnt(8)" ::: "memory");
        else if (t == NT - 3) asm volatile("s_waitcnt vmcnt(4)" ::: "memory");
        else if (t == NT - 2) asm volatile("s_waitcnt vmcnt(0)" ::: "memory");
        if (t < NT - 1) {
            __builtin_amdgcn_s_barrier();
            __builtin_amdgcn_sched_barrier(0);
        }
    }

    if constexpr (!COLMAX) {
        // C/D layout: col = fr, row = kq*4 + r  [verified m89/m91]
        u16* C = Cb + (size_t)batch * M * N + (size_t)(mt * 256 + wr * 128) * N + nc * 256 + wc * 64;
        #pragma unroll
        for (int m = 0; m < 8; ++m)
            #pragma unroll
            for (int n = 0; n < 4; ++n)
                #pragma unroll
                for (int r = 0; r < 4; ++r)
                    C[(size_t)(m * 16 + kq * 4 + r) * N + n * 16 + fr] = f2bf(acc[m][n][r]);
    } else {
        __shared__ float cmax[2][256];
        #pragma unroll
        for (int n = 0; n < 4; ++n) {
            float v = -3.4e38f;
            #pragma unroll
            for (int m = 0; m < 8; ++m)
                #pragma unroll
                for (int r = 0; r < 4; ++r)
                    v = fmaxf(v, acc[m][n][r]);
            v = fmaxf(v, __shfl_xor(v, 16));
            v = fmaxf(v, __shfl_xor(v, 32));
            if (lane < 16) cmax[wr][wc * 64 + n * 16 + fr] = v;
        }
        __syncthreads();
        if (tid < 256) {
            float v = fmaxf(cmax[0][tid], cmax[1][tid]);
            Pb[((size_t)batch * MT + mt) * N + nc * 256 + tid] = v;
        }
    }
}

// alpha[b][t] = tanh(max over 8 row-tiles)
__global__ void k_alpha(const float* __restrict__ Pb, float* __restrict__ alpha) {
    int idx = blockIdx.x * 256 + threadIdx.x;   // NB*LTD
    int b = idx / LTD, tt = idx % LTD;
    float m = -3.4e38f;
    #pragma unroll
    for (int lt = 0; lt < 8; ++lt)
        m = fmaxf(m, Pb[((size_t)b * 8 + lt) * LTD + tt]);
    alpha[idx] = tanhf(m);
}

__global__ void k_ht_partial(const float* __restrict__ T, const float* __restrict__ alpha,
                             float* __restrict__ p2) {
    int bx = blockIdx.x;            // NB*3*8
    int tc = bx & 7;
    int r  = bx >> 3;
    int dc = r % 3, b = r / 3;
    int d = dc * 256 + threadIdx.x;
    const float* Tp = T + (size_t)b * LTD * DD + (size_t)tc * 256 * DD + d;
    const float* al = alpha + b * LTD + tc * 256;
    float s = 0.f;
    for (int t2 = 0; t2 < 256; ++t2)
        s += al[t2] * Tp[(size_t)t2 * DD];
    p2[((size_t)b * 8 + tc) * DD + d] = s;
}

__global__ void k_ht_reduce(const float* __restrict__ p2, float* __restrict__ out) {
    int idx = blockIdx.x * 256 + threadIdx.x;   // NB*DD
    int b = idx / DD, d = idx % DD;
    float s = 0.f;
    #pragma unroll
    for (int tc = 0; tc < 8; ++tc)
        s += p2[((size_t)b * 8 + tc) * DD + d];
    out[idx] = s;
}

extern "C" void kernel_launch(void* const* d_in, const int* in_sizes, int n_in,
                              void* d_out, int out_size, void* d_ws, size_t ws_size,
                              hipStream_t stream) {
    const float* H = (const float*)d_in[0];
    const float* T = (const float*)d_in[1];
    const float* W = (const float*)d_in[2];
    float* out = (float*)d_out;

    char* ws = (char*)d_ws;
    size_t off = 0;
    auto carve = [&](size_t bytes) -> void* {
        void* p = ws + off;
        off += (bytes + 255) & ~(size_t)255;
        return p;
    };
    u16*   R1    = (u16*)carve((size_t)NB * LHD * DD * 2);   // Hb, later reused as Tb
    u16*   z1    = (u16*)carve((size_t)NB * LHD * DD * 2);
    u16*   WT    = (u16*)carve((size_t)DD * DD * 2);
    float* Pb    = (float*)carve((size_t)NB * 8 * LTD * 4);
    float* alpha = (float*)carve((size_t)NB * LTD * 4);
    float* p2    = (float*)carve((size_t)NB * 8 * DD * 4);

    if (ws_size < off) return;

    const int n4 = NB * LHD * DD / 4;

    // 1. Hb = bf16(H)
    k_convert<<<4096, 256, 0, stream>>>(H, R1, n4);
    // 2. WT = bf16(W^T)
    k_transpose_w<<<(DD * DD) / 256, 256, 0, stream>>>(W, WT);
    // 3. z1 = Hb @ W   (grid 32*8*3 = 768)
    k_gemm256<false, LHD, DD, true>
        <<<NB * (LHD/256) * (DD/256), 512, 0, stream>>>(R1, WT, z1, nullptr);
    // 4. Tb = bf16(T) into R1 (Hb dead; stream-ordered)
    k_convert<<<4096, 256, 0, stream>>>(T, R1, n4);
    // 5. colmax(z1 @ T^T)  (grid 32*8*8 = 2048)
    k_gemm256<true, LHD, LTD, false>
        <<<NB * (LHD/256) * (LTD/256), 512, 0, stream>>>(z1, R1, nullptr, Pb);
    // 6. alpha = tanh(max)
    k_alpha<<<NB * LTD / 256, 256, 0, stream>>>(Pb, alpha);
    // 7-8. HT = alpha @ T (f32)
    k_ht_partial<<<NB * 3 * 8, 256, 0, stream>>>(T, alpha, p2);
    k_ht_reduce<<<NB * DD / 256, 256, 0, stream>>>(p2, out);
}

// Round 3
// 458.324 us; speedup vs baseline: 1.3532x; 1.0719x over previous
//
#include <hip/hip_runtime.h>
#include <hip/hip_bf16.h>
#include <stdint.h>

// Problem: B=32, LH=2048, LT=2048, D=768
//   z1 = H @ W ; alpha = tanh(colmax(z1 @ T^T)) ; HT = alpha @ T
#define NB 32
#define LHD 2048
#define LTD 2048
#define DD 768

using bf16x8 = __attribute__((ext_vector_type(8))) __bf16;
using f32x4  = __attribute__((ext_vector_type(4))) float;
typedef unsigned short u16;

__device__ __forceinline__ u16 f2bf(float f) {
    union { float f; uint32_t u; } v; v.f = f;
    uint32_t u = v.u + 0x7FFFu + ((v.u >> 16) & 1u);
    return (u16)(u >> 16);
}

__device__ __forceinline__ void glds16(const u16* g, u16* l) {
    __builtin_amdgcn_global_load_lds(
        (const __attribute__((address_space(1))) unsigned int*)g,
        (__attribute__((address_space(3))) unsigned int*)l,
        16, 0, 0);
}

// ---------------- conversion kernels ----------------
__global__ void k_convert(const float* __restrict__ in, u16* __restrict__ out, int n4) {
    int i = blockIdx.x * 256 + threadIdx.x;
    int stride = gridDim.x * 256;
    for (; i < n4; i += stride) {
        float4 v = reinterpret_cast<const float4*>(in)[i];
        ushort4 o;
        o.x = f2bf(v.x); o.y = f2bf(v.y); o.z = f2bf(v.z); o.w = f2bf(v.w);
        reinterpret_cast<ushort4*>(out)[i] = o;
    }
}

__global__ void k_transpose_w(const float* __restrict__ W, u16* __restrict__ WT) {
    int idx = blockIdx.x * 256 + threadIdx.x;
    int k = idx / DD, n = idx % DD;
    WT[(size_t)n * DD + k] = f2bf(W[idx]);
}

// ---------------- 256x256-tile deep-pipelined GEMM, 2-phase per K-tile ----------------
// A [M,K] row-major bf16; Bt [N,K] row-major bf16; K=768.
// 8 waves (2Mx4N), per-wave 128x64 output; BK=32; 4-buffer LDS ring;
// stage t+3 during tile t; vmcnt(8) counted waits; XOR-swizzled LDS;
// per K-tile: 2 phases x {ds_read, stage-issue, barrier, lgkmcnt(0), 16 MFMA, barrier}.
template<bool COLMAX, int M, int N, bool SHARED_B>
__global__ __launch_bounds__(512, 2)
void k_gemm256(const u16* __restrict__ Ab, const u16* __restrict__ Bb,
               u16* __restrict__ Cb, float* __restrict__ Pb)
{
    constexpr int K  = DD;       // 768
    constexpr int BK = 32;
    constexpr int NT = K / BK;   // 24
    constexpr int MT = M / 256, NTC = N / 256, TPB = MT * NTC;
    static_assert(K % BK == 0, "K");

    // bijective XCD-aware swizzle (grids are multiples of 8)
    const int nwg = gridDim.x;
    const int w   = ((blockIdx.x & 7) * (nwg >> 3)) + (blockIdx.x >> 3);
    const int batch = w / TPB;
    const int rem   = w % TPB;
    const int mt = rem / NTC, nc = rem % NTC;

    const u16* A  = Ab + (size_t)batch * M * K + (size_t)mt * 256 * K;
    const u16* Bt = Bb + (SHARED_B ? (size_t)0 : (size_t)batch * N * K) + (size_t)nc * 256 * K;

    // A ring: [4][256][32] bf16 @ elem 0 (64KB); B ring @ elem 32768 (64KB)
    __shared__ __align__(16) u16 smem[65536];

    const int tid  = threadIdx.x;
    const int wave = tid >> 6;
    const int lane = tid & 63;
    const int wr = wave >> 2, wc = wave & 3;   // 2x4 wave grid
    const int fr = lane & 15, kq = lane >> 4;

    // --- staging address precompute (pre-swizzled GLOBAL source, linear LDS dest) ---
    // chunk c = wave*128 + j*64 + lane ; phys row rp=c>>2, phys 16B slot cp=c&3
    // logical k-chunk stored at cp is kq' = cp ^ ((rp>>1)&3)
    const int c0  = wave * 128 + lane;
    const int c1  = c0 + 64;
    const int rp0 = c0 >> 2, rp1 = c1 >> 2;
    const int g0  = rp0 * K + ((((c0 & 3) ^ ((rp0 >> 1) & 3))) << 3);  // elems
    const int g1  = rp1 * K + ((((c1 & 3) ^ ((rp1 >> 1) & 3))) << 3);
    const int sA  = wave * 1024;  // this wave's chunk block (elems), +512 for j=1

    // --- fragment read byte offsets (within one buffer), same XOR on read ---
    const int xr  = (fr >> 1) & 3;
    const int afb = (wr * 128 + fr) * 64 + ((kq ^ xr) << 4);
    const int bfb = (wc * 64  + fr) * 64 + ((kq ^ xr) << 4);

    // staging halves: half 0 = A tile (2 issues), half 1 = B tile (2 issues)
    auto stageA = [&](int buf, int t) {
        const u16* Ag = A + t * BK;
        u16* s = smem + buf * 8192;
        glds16(Ag + g0, s + sA);
        glds16(Ag + g1, s + sA + 512);
    };
    auto stageB = [&](int buf, int t) {
        const u16* Bg = Bt + t * BK;
        u16* s = smem + 32768 + buf * 8192;
        glds16(Bg + g0, s + sA);
        glds16(Bg + g1, s + sA + 512);
    };

    f32x4 acc[8][4] = {};

    // prologue: tiles 0,1,2 in flight; wait until tile 0 landed (12 issued, <=8 out)
    stageA(0, 0); stageB(0, 0);
    stageA(1, 1); stageB(1, 1);
    stageA(2, 2); stageB(2, 2);
    asm volatile("s_waitcnt vmcnt(8)" ::: "memory");
    __builtin_amdgcn_s_barrier();
    __builtin_amdgcn_sched_barrier(0);

    #pragma unroll 4
    for (int t = 0; t < NT; ++t) {
        const int buf = t & 3;
        const char* ca = (const char*)smem + buf * 16384;
        const char* cb = ca + 65536;
        const bool pf = (t + 3 < NT);

        // ================= phase 0: m-half 0 =================
        bf16x8 a0[4], a1[4], bv[4];
        #pragma unroll
        for (int m = 0; m < 4; ++m)
            a0[m] = *(const bf16x8*)(ca + afb + m * 1024);
        #pragma unroll
        for (int n = 0; n < 4; ++n)
            bv[n] = *(const bf16x8*)(cb + bfb + n * 1024);
        if (pf) stageA((t + 3) & 3, t + 3);   // WAR-safe: buf last read at tile t-1

        __builtin_amdgcn_s_barrier();
        asm volatile("s_waitcnt lgkmcnt(0)" ::: "memory");
        __builtin_amdgcn_sched_barrier(0);
        __builtin_amdgcn_s_setprio(1);
        #pragma unroll
        for (int m = 0; m < 4; ++m)
            #pragma unroll
            for (int n = 0; n < 4; ++n)
                acc[m][n] = __builtin_amdgcn_mfma_f32_16x16x32_bf16(a0[m], bv[n], acc[m][n], 0, 0, 0);
        __builtin_amdgcn_s_setprio(0);
        __builtin_amdgcn_s_barrier();

        // ================= phase 1: m-half 1 =================
        #pragma unroll
        for (int m = 0; m < 4; ++m)
            a1[m] = *(const bf16x8*)(ca + afb + (m + 4) * 1024);
        if (pf) stageB((t + 3) & 3, t + 3);

        __builtin_amdgcn_s_barrier();
        asm volatile("s_waitcnt lgkmcnt(0)" ::: "memory");
        __builtin_amdgcn_sched_barrier(0);
        __builtin_amdgcn_s_setprio(1);
        #pragma unroll
        for (int m = 0; m < 4; ++m)
            #pragma unroll
            for (int n = 0; n < 4; ++n)
                acc[m + 4][n] = __builtin_amdgcn_mfma_f32_16x16x32_bf16(a1[m], bv[n], acc[m + 4][n], 0, 0, 0);
        __builtin_amdgcn_s_setprio(0);

        // counted drain once per K-tile: leave tiles t+2,t+3 in flight
        if (t < NT - 3)       asm volatile("s_waitcnt vmcnt(8)" ::: "memory");
        else if (t == NT - 3) asm volatile("s_waitcnt vmcnt(4)" ::: "memory");
        else if (t == NT - 2) asm volatile("s_waitcnt vmcnt(0)" ::: "memory");
        if (t < NT - 1) {
            __builtin_amdgcn_s_barrier();
            __builtin_amdgcn_sched_barrier(0);
        }
    }

    if constexpr (!COLMAX) {
        // C/D layout: col = fr, row = kq*4 + r  [verified m89/m91]
        u16* C = Cb + (size_t)batch * M * N + (size_t)(mt * 256 + wr * 128) * N + nc * 256 + wc * 64;
        #pragma unroll
        for (int m = 0; m < 8; ++m)
            #pragma unroll
            for (int n = 0; n < 4; ++n)
                #pragma unroll
                for (int r = 0; r < 4; ++r)
                    C[(size_t)(m * 16 + kq * 4 + r) * N + n * 16 + fr] = f2bf(acc[m][n][r]);
    } else {
        __shared__ float cmax[2][256];
        #pragma unroll
        for (int n = 0; n < 4; ++n) {
            float v = -3.4e38f;
            #pragma unroll
            for (int m = 0; m < 8; ++m)
                #pragma unroll
                for (int r = 0; r < 4; ++r)
                    v = fmaxf(v, acc[m][n][r]);
            v = fmaxf(v, __shfl_xor(v, 16));
            v = fmaxf(v, __shfl_xor(v, 32));
            if (lane < 16) cmax[wr][wc * 64 + n * 16 + fr] = v;
        }
        __syncthreads();
        if (tid < 256) {
            float v = fmaxf(cmax[0][tid], cmax[1][tid]);
            Pb[((size_t)batch * MT + mt) * N + nc * 256 + tid] = v;
        }
    }
}

// alpha[b][t] = tanh(max over 8 row-tiles)
__global__ void k_alpha(const float* __restrict__ Pb, float* __restrict__ alpha) {
    int idx = blockIdx.x * 256 + threadIdx.x;   // NB*LTD
    int b = idx / LTD, tt = idx % LTD;
    float m = -3.4e38f;
    #pragma unroll
    for (int lt = 0; lt < 8; ++lt)
        m = fmaxf(m, Pb[((size_t)b * 8 + lt) * LTD + tt]);
    alpha[idx] = tanhf(m);
}

__global__ void k_ht_partial(const float* __restrict__ T, const float* __restrict__ alpha,
                             float* __restrict__ p2) {
    int bx = blockIdx.x;            // NB*3*8
    int tc = bx & 7;
    int r  = bx >> 3;
    int dc = r % 3, b = r / 3;
    int d = dc * 256 + threadIdx.x;
    const float* Tp = T + (size_t)b * LTD * DD + (size_t)tc * 256 * DD + d;
    const float* al = alpha + b * LTD + tc * 256;
    float s = 0.f;
    for (int t2 = 0; t2 < 256; ++t2)
        s += al[t2] * Tp[(size_t)t2 * DD];
    p2[((size_t)b * 8 + tc) * DD + d] = s;
}

__global__ void k_ht_reduce(const float* __restrict__ p2, float* __restrict__ out) {
    int idx = blockIdx.x * 256 + threadIdx.x;   // NB*DD
    int b = idx / DD, d = idx % DD;
    float s = 0.f;
    #pragma unroll
    for (int tc = 0; tc < 8; ++tc)
        s += p2[((size_t)b * 8 + tc) * DD + d];
    out[idx] = s;
}

extern "C" void kernel_launch(void* const* d_in, const int* in_sizes, int n_in,
                              void* d_out, int out_size, void* d_ws, size_t ws_size,
                              hipStream_t stream) {
    const float* H = (const float*)d_in[0];
    const float* T = (const float*)d_in[1];
    const float* W = (const float*)d_in[2];
    float* out = (float*)d_out;

    char* ws = (char*)d_ws;
    size_t off = 0;
    auto carve = [&](size_t bytes) -> void* {
        void* p = ws + off;
        off += (bytes + 255) & ~(size_t)255;
        return p;
    };
    u16*   R1    = (u16*)carve((size_t)NB * LHD * DD * 2);   // Hb, later reused as Tb
    u16*   z1    = (u16*)carve((size_t)NB * LHD * DD * 2);
    u16*   WT    = (u16*)carve((size_t)DD * DD * 2);
    float* Pb    = (float*)carve((size_t)NB * 8 * LTD * 4);
    float* alpha = (float*)carve((size_t)NB * LTD * 4);
    float* p2    = (float*)carve((size_t)NB * 8 * DD * 4);

    if (ws_size < off) return;

    const int n4 = NB * LHD * DD / 4;

    // 1. Hb = bf16(H)
    k_convert<<<4096, 256, 0, stream>>>(H, R1, n4);
    // 2. WT = bf16(W^T)
    k_transpose_w<<<(DD * DD) / 256, 256, 0, stream>>>(W, WT);
    // 3. z1 = Hb @ W   (grid 32*8*3 = 768)
    k_gemm256<false, LHD, DD, true>
        <<<NB * (LHD/256) * (DD/256), 512, 0, stream>>>(R1, WT, z1, nullptr);
    // 4. Tb = bf16(T) into R1 (Hb dead; stream-ordered)
    k_convert<<<4096, 256, 0, stream>>>(T, R1, n4);
    // 5. colmax(z1 @ T^T)  (grid 32*8*8 = 2048)
    k_gemm256<true, LHD, LTD, false>
        <<<NB * (LHD/256) * (LTD/256), 512, 0, stream>>>(z1, R1, nullptr, Pb);
    // 6. alpha = tanh(max)
    k_alpha<<<NB * LTD / 256, 256, 0, stream>>>(Pb, alpha);
    // 7-8. HT = alpha @ T (f32)
    k_ht_partial<<<NB * 3 * 8, 256, 0, stream>>>(T, alpha, p2);
    k_ht_reduce<<<NB * DD / 256, 256, 0, stream>>>(p2, out);
}